// Round 1
// baseline (374.406 us; speedup 1.0000x reference)
//
#include <hip/hip_runtime.h>
#include <hip/hip_bf16.h>
#include <stdint.h>

typedef __attribute__((ext_vector_type(4))) float f32x4;
typedef __attribute__((ext_vector_type(8))) __bf16 bf16x8;
typedef __attribute__((ext_vector_type(8))) unsigned short u16x8;

__device__ __forceinline__ unsigned short f2bf(float f){
  uint32_t u = __builtin_bit_cast(uint32_t, f);
  u += 0x7FFFu + ((u >> 16) & 1u);
  return (unsigned short)(u >> 16);
}
__device__ __forceinline__ float bf2f(unsigned short h){
  return __builtin_bit_cast(float, ((uint32_t)h) << 16);
}

// ---------------- fp32 -> bf16 convert (weights) ----------------
__global__ __launch_bounds__(256) void f32_to_bf16(const float* __restrict__ in,
                                                   unsigned short* __restrict__ out, int n){
  int i = (blockIdx.x * 256 + threadIdx.x) * 8;
  if (i + 8 <= n) {
    float4 a = *(const float4*)&in[i];
    float4 b = *(const float4*)&in[i + 4];
    u16x8 o;
    o[0]=f2bf(a.x); o[1]=f2bf(a.y); o[2]=f2bf(a.z); o[3]=f2bf(a.w);
    o[4]=f2bf(b.x); o[5]=f2bf(b.y); o[6]=f2bf(b.z); o[7]=f2bf(b.w);
    *(u16x8*)&out[i] = o;
  }
}

// ---------------- GroupNorm stats: one block per (b,group) ----------------
// group = 16 contiguous channels x 4096 px = 65536 contiguous floats
__global__ __launch_bounds__(256) void gn_stats(const float* __restrict__ x,
                                                float* __restrict__ stats){
  int grp = blockIdx.x; // b*32+g, 128 total
  const float* p = x + (size_t)grp * 65536;
  float s = 0.f, ss = 0.f;
  for (int i = threadIdx.x; i < 16384; i += 256) {
    float4 v = *(const float4*)(p + (size_t)i * 4);
    s  += v.x + v.y + v.z + v.w;
    ss += v.x*v.x + v.y*v.y + v.z*v.z + v.w*v.w;
  }
  for (int off = 32; off; off >>= 1) { s += __shfl_down(s, off); ss += __shfl_down(ss, off); }
  __shared__ float red[8];
  int w = threadIdx.x >> 6;
  if ((threadIdx.x & 63) == 0) { red[w] = s; red[w + 4] = ss; }
  __syncthreads();
  if (threadIdx.x == 0) {
    s  = red[0] + red[1] + red[2] + red[3];
    ss = red[4] + red[5] + red[6] + red[7];
    float mean = s * (1.f / 65536.f);
    float var  = ss * (1.f / 65536.f) - mean * mean;
    stats[grp * 2]     = mean;
    stats[grp * 2 + 1] = rsqrtf(var + 1e-6f);
  }
}

// ---------------- GN apply + transpose: x[b][c][p] -> hn_t[b][p][c] bf16 ----------------
__global__ __launch_bounds__(256) void gn_apply(const float* __restrict__ x,
                                                const float* __restrict__ stats,
                                                const float* __restrict__ gamma,
                                                const float* __restrict__ beta,
                                                unsigned short* __restrict__ hn_t){
  __shared__ float tile[32][33];
  int b  = blockIdx.z;
  int c0 = blockIdx.y * 32;
  int p0 = blockIdx.x * 32;
  int tx = threadIdx.x & 31, ty = threadIdx.x >> 5;
  const float* xb = x + (size_t)b * 512 * 4096;
#pragma unroll
  for (int i = 0; i < 32; i += 8)
    tile[ty + i][tx] = xb[(size_t)(c0 + ty + i) * 4096 + p0 + tx];
  __syncthreads();
  unsigned short* hb = hn_t + (size_t)b * 4096 * 512;
  int c = c0 + tx;
  float mean = stats[(b * 32 + (c >> 4)) * 2];
  float rstd = stats[(b * 32 + (c >> 4)) * 2 + 1];
  float ga = gamma[c], be = beta[c];
#pragma unroll
  for (int i = 0; i < 32; i += 8) {
    float v = tile[tx][ty + i];
    hb[(size_t)(p0 + ty + i) * 512 + c] = f2bf((v - mean) * rstd * ga + be);
  }
}

// ---------------- GEMM: C[M,N] = A[M,K] * B[N,K]^T (bf16 in, fp32 accum) ----------------
// BIAS: 0 none, 1 per-col bias[n], 2 per-row bias[m]
// FINAL: write fp32 to OUTF[b][col][row&4095] + resid + bias[col]  (row = b*4096+p)
template<int BIAS, bool FINAL>
__global__ __launch_bounds__(256)
void gemm_bt(const unsigned short* __restrict__ A,
             const unsigned short* __restrict__ B,
             unsigned short* __restrict__ C,
             float* __restrict__ OUTF,
             const float* __restrict__ resid,
             const float* __restrict__ bias,
             int M, int N, int K, float scale,
             size_t sA, size_t sB, size_t sC)
{
  __shared__ __align__(16) unsigned short As[128 * 32];
  __shared__ __align__(16) unsigned short Bs[128 * 32];
  const unsigned short* Ab = A + (size_t)blockIdx.z * sA;
  const unsigned short* Bb = B + (size_t)blockIdx.z * sB;
  const int brow = blockIdx.x * 128;
  const int bcol = blockIdx.y * 128;
  const int t = threadIdx.x;
  const int lane = t & 63;
  const int wid = t >> 6;
  const int wr = wid >> 1, wc = wid & 1;

  const f32x4 zero = {0.f, 0.f, 0.f, 0.f};
  f32x4 acc[4][4];
#pragma unroll
  for (int m = 0; m < 4; m++)
#pragma unroll
    for (int n = 0; n < 4; n++) acc[m][n] = zero;

  // staging: 512 16B-chunks per tile; thread t does chunks t and t+256
  // chunk q: row r=q>>2, slot s=q&3 (8 bf16). LDS slot swizzle: s ^= (r>>1)&3
  const int q0 = t, q1 = t + 256;
  const int r0 = q0 >> 2, s0 = q0 & 3;
  const int r1 = q1 >> 2, s1 = q1 & 3;
  const int w0 = r0 * 32 + ((s0 ^ ((r0 >> 1) & 3)) * 8);
  const int w1 = r1 * 32 + ((s1 ^ ((r1 >> 1) & 3)) * 8);
  const size_t ga0 = (size_t)(brow + r0) * K + s0 * 8;
  const size_t ga1 = (size_t)(brow + r1) * K + s1 * 8;
  const size_t gb0 = (size_t)(bcol + r0) * K + s0 * 8;
  const size_t gb1 = (size_t)(bcol + r1) * K + s1 * 8;

  const int arow = wr * 64 + (lane & 15);
  const int brw  = wc * 64 + (lane & 15);
  const int ka  = (((lane >> 4) ^ ((arow >> 1) & 3)) * 8);  // invariant under +16 rows
  const int kb2 = (((lane >> 4) ^ ((brw  >> 1) & 3)) * 8);

  const int nk = K >> 5;
  for (int kt = 0; kt < nk; ++kt) {
    __syncthreads();
    const size_t ko = (size_t)kt * 32;
    *(uint4*)&As[w0] = *(const uint4*)&Ab[ga0 + ko];
    *(uint4*)&As[w1] = *(const uint4*)&Ab[ga1 + ko];
    *(uint4*)&Bs[w0] = *(const uint4*)&Bb[gb0 + ko];
    *(uint4*)&Bs[w1] = *(const uint4*)&Bb[gb1 + ko];
    __syncthreads();
    bf16x8 af[4], bfr[4];
#pragma unroll
    for (int m = 0; m < 4; m++)
      af[m] = __builtin_bit_cast(bf16x8, *(const u16x8*)&As[(arow + m * 16) * 32 + ka]);
#pragma unroll
    for (int n = 0; n < 4; n++)
      bfr[n] = __builtin_bit_cast(bf16x8, *(const u16x8*)&Bs[(brw + n * 16) * 32 + kb2]);
#pragma unroll
    for (int m = 0; m < 4; m++)
#pragma unroll
      for (int n = 0; n < 4; n++)
        acc[m][n] = __builtin_amdgcn_mfma_f32_16x16x32_bf16(af[m], bfr[n], acc[m][n], 0, 0, 0);
  }

  // epilogue: C/D layout col=lane&15, row=(lane>>4)*4+j
  const int cl = lane & 15;
  const int rg = (lane >> 4) * 4;
  if (!FINAL) {
    unsigned short* Cb = C + (size_t)blockIdx.z * sC;
#pragma unroll
    for (int m = 0; m < 4; m++) {
#pragma unroll
      for (int n = 0; n < 4; n++) {
        const int col = bcol + wc * 64 + n * 16 + cl;
        const float bcv = (BIAS == 1) ? bias[col] : 0.f;
#pragma unroll
        for (int j = 0; j < 4; j++) {
          const int row = brow + wr * 64 + m * 16 + rg + j;
          float v = acc[m][n][j] * scale + bcv + ((BIAS == 2) ? bias[row] : 0.f);
          Cb[(size_t)row * N + col] = f2bf(v);
        }
      }
    }
  } else {
#pragma unroll
    for (int m = 0; m < 4; m++) {
      const int row = brow + wr * 64 + m * 16 + rg;
      const int bb = row >> 12;
      const int p  = row & 4095;
#pragma unroll
      for (int n = 0; n < 4; n++) {
        const int col = bcol + wc * 64 + n * 16 + cl;
        const size_t idx = ((size_t)bb * 512 + col) * 4096 + p;
        const float4 xv = *(const float4*)&resid[idx];
        const float bv = bias[col];
        float4 ov;
        ov.x = acc[m][n][0] + xv.x + bv;
        ov.y = acc[m][n][1] + xv.y + bv;
        ov.z = acc[m][n][2] + xv.z + bv;
        ov.w = acc[m][n][3] + xv.w + bv;
        *(float4*)&OUTF[idx] = ov;
      }
    }
  }
}

// ---------------- masked softmax, in place on bf16 score rows ----------------
// P[b][qi][ki] (bf16), mask[b][ki] (fp32, 0/1); p_k = m_k*exp(s_k - max) / sum
__global__ __launch_bounds__(256) void softmax_mask(unsigned short* __restrict__ P,
                                                    const float* __restrict__ mask){
  const int qi = blockIdx.x, b = blockIdx.y;
  unsigned short* row = P + ((size_t)b * 4096 + qi) * 4096;
  const float* mrow = mask + (size_t)b * 4096;
  const int t = threadIdx.x;
  float s[16], mk[16];
  float mx = -1e30f;
#pragma unroll
  for (int i = 0; i < 2; i++) {
    const int idx = (i * 256 + t) * 8;
    u16x8 sv = *(const u16x8*)&row[idx];
    float4 m0 = *(const float4*)&mrow[idx];
    float4 m1 = *(const float4*)&mrow[idx + 4];
    float ml[8] = {m0.x, m0.y, m0.z, m0.w, m1.x, m1.y, m1.z, m1.w};
#pragma unroll
    for (int j = 0; j < 8; j++) {
      float v = bf2f(sv[j]);
      s[i * 8 + j] = v;
      mk[i * 8 + j] = ml[j];
      if (ml[j] != 0.f) mx = fmaxf(mx, v);
    }
  }
  for (int off = 32; off; off >>= 1) mx = fmaxf(mx, __shfl_xor(mx, off));
  __shared__ float redm[4];
  const int w = t >> 6;
  if ((t & 63) == 0) redm[w] = mx;
  __syncthreads();
  mx = fmaxf(fmaxf(redm[0], redm[1]), fmaxf(redm[2], redm[3]));
  float p[16], sum = 0.f;
#pragma unroll
  for (int i = 0; i < 16; i++) {
    float v = mk[i] * __expf(s[i] - mx);
    p[i] = v;
    sum += v;
  }
  for (int off = 32; off; off >>= 1) sum += __shfl_xor(sum, off);
  __shared__ float reds[4];
  if ((t & 63) == 0) reds[w] = sum;
  __syncthreads();
  sum = reds[0] + reds[1] + reds[2] + reds[3];
  const float inv = 1.f / sum;
#pragma unroll
  for (int i = 0; i < 2; i++) {
    const int idx = (i * 256 + t) * 8;
    u16x8 ov;
#pragma unroll
    for (int j = 0; j < 8; j++) ov[j] = f2bf(p[i * 8 + j] * inv);
    *(u16x8*)&row[idx] = ov;
  }
}

extern "C" void kernel_launch(void* const* d_in, const int* in_sizes, int n_in,
                              void* d_out, int out_size, void* d_ws, size_t ws_size,
                              hipStream_t stream) {
  const float* x     = (const float*)d_in[0];
  const float* mask  = (const float*)d_in[1];
  const float* gamma = (const float*)d_in[2];
  const float* beta  = (const float*)d_in[3];
  const float* Wq    = (const float*)d_in[4];
  const float* bq    = (const float*)d_in[5];
  const float* Wk    = (const float*)d_in[6];
  const float* bk    = (const float*)d_in[7];
  const float* Wv    = (const float*)d_in[8];
  const float* bv    = (const float*)d_in[9];
  const float* Wo    = (const float*)d_in[10];
  const float* bo    = (const float*)d_in[11];
  float* out = (float*)d_out;

  size_t off = 0;
  auto nxt = [&](size_t bytes) -> void* {
    void* p = (char*)d_ws + off;
    off += (bytes + 255) & ~(size_t)255;
    return p;
  };
  float* stats          = (float*)nxt(256 * sizeof(float));
  unsigned short* Wqb   = (unsigned short*)nxt((size_t)512 * 512 * 2);
  unsigned short* Wkb   = (unsigned short*)nxt((size_t)512 * 512 * 2);
  unsigned short* Wvb   = (unsigned short*)nxt((size_t)512 * 512 * 2);
  unsigned short* Wob   = (unsigned short*)nxt((size_t)512 * 512 * 2);
  unsigned short* hnt   = (unsigned short*)nxt((size_t)16384 * 512 * 2); // [b*4096+p][c]
  unsigned short* qt    = (unsigned short*)nxt((size_t)16384 * 512 * 2);
  unsigned short* ktb   = (unsigned short*)nxt((size_t)16384 * 512 * 2);
  unsigned short* vcm   = (unsigned short*)nxt((size_t)16384 * 512 * 2); // [b][c][p]
  unsigned short* ot    = (unsigned short*)nxt((size_t)16384 * 512 * 2); // [b*4096+p][c]
  unsigned short* P     = (unsigned short*)nxt((size_t)4 * 4096 * 4096 * 2);

  f32_to_bf16<<<128, 256, 0, stream>>>(Wq, Wqb, 262144);
  f32_to_bf16<<<128, 256, 0, stream>>>(Wk, Wkb, 262144);
  f32_to_bf16<<<128, 256, 0, stream>>>(Wv, Wvb, 262144);
  f32_to_bf16<<<128, 256, 0, stream>>>(Wo, Wob, 262144);

  gn_stats<<<128, 256, 0, stream>>>(x, stats);
  gn_apply<<<dim3(128, 16, 4), 256, 0, stream>>>(x, stats, gamma, beta, hnt);

  // Q, K: [16384,512] = hn_t[16384,512] x W[512,512]^T  (+ per-col bias)
  gemm_bt<1, false><<<dim3(128, 4, 1), 256, 0, stream>>>(hnt, Wqb, qt, nullptr, nullptr, bq,
                                                         16384, 512, 512, 1.f, 0, 0, 0);
  gemm_bt<1, false><<<dim3(128, 4, 1), 256, 0, stream>>>(hnt, Wkb, ktb, nullptr, nullptr, bk,
                                                         16384, 512, 512, 1.f, 0, 0, 0);
  // V channel-major: v_cm[b][c][p] = Wv[512,512] x hn_t[b][4096,512]^T (+ per-row bias)
  gemm_bt<2, false><<<dim3(4, 32, 4), 256, 0, stream>>>(Wvb, hnt, vcm, nullptr, nullptr, bv,
                                                        512, 4096, 512, 1.f,
                                                        0, (size_t)4096 * 512, (size_t)512 * 4096);
  // scores: P[b][qi][ki] = qt[b] x kt[b]^T * C^-0.5  (bf16 out)
  gemm_bt<0, false><<<dim3(32, 32, 4), 256, 0, stream>>>(qt, ktb, P, nullptr, nullptr, nullptr,
                                                         4096, 4096, 512, 0.044194173824159216f,
                                                         (size_t)4096 * 512, (size_t)4096 * 512,
                                                         (size_t)4096 * 4096);
  softmax_mask<<<dim3(4096, 4), 256, 0, stream>>>(P, mask);
  // PV: ot[b][qi][c] = P[b] x v_cm[b]^T
  gemm_bt<0, false><<<dim3(32, 4, 4), 256, 0, stream>>>(P, vcm, ot, nullptr, nullptr, nullptr,
                                                        4096, 512, 4096, 1.f,
                                                        (size_t)4096 * 4096, (size_t)512 * 4096,
                                                        (size_t)4096 * 512);
  // O-projection + residual + bias, transposed write to d_out[b][c][p]
  gemm_bt<0, true><<<dim3(128, 4, 1), 256, 0, stream>>>(ot, Wob, nullptr, out, x, bo,
                                                        16384, 512, 512, 1.f, 0, 0, 0);
}

// Round 2
// 372.150 us; speedup vs baseline: 1.0061x; 1.0061x over previous
//
#include <hip/hip_runtime.h>
#include <hip/hip_bf16.h>
#include <stdint.h>

typedef __attribute__((ext_vector_type(4))) float f32x4;
typedef __attribute__((ext_vector_type(8))) __bf16 bf16x8;
typedef __attribute__((ext_vector_type(8))) unsigned short u16x8;

__device__ __forceinline__ unsigned short f2bf(float f){
  uint32_t u = __builtin_bit_cast(uint32_t, f);
  u += 0x7FFFu + ((u >> 16) & 1u);
  return (unsigned short)(u >> 16);
}
__device__ __forceinline__ float bf2f(unsigned short h){
  return __builtin_bit_cast(float, ((uint32_t)h) << 16);
}

__device__ __forceinline__ void gl_lds16(const unsigned short* g, unsigned short* l){
  __builtin_amdgcn_global_load_lds(
      (const __attribute__((address_space(1))) uint32_t*)g,
      (__attribute__((address_space(3))) uint32_t*)l, 16, 0, 0);
}

// ---------------- fp32 -> bf16 convert (weights) ----------------
__global__ __launch_bounds__(256) void f32_to_bf16(const float* __restrict__ in,
                                                   unsigned short* __restrict__ out, int n){
  int i = (blockIdx.x * 256 + threadIdx.x) * 8;
  if (i + 8 <= n) {
    float4 a = *(const float4*)&in[i];
    float4 b = *(const float4*)&in[i + 4];
    u16x8 o;
    o[0]=f2bf(a.x); o[1]=f2bf(a.y); o[2]=f2bf(a.z); o[3]=f2bf(a.w);
    o[4]=f2bf(b.x); o[5]=f2bf(b.y); o[6]=f2bf(b.z); o[7]=f2bf(b.w);
    *(u16x8*)&out[i] = o;
  }
}

// ---------------- GroupNorm stats: one block per (b,group) ----------------
__global__ __launch_bounds__(256) void gn_stats(const float* __restrict__ x,
                                                float* __restrict__ stats){
  int grp = blockIdx.x; // b*32+g, 128 total
  const float* p = x + (size_t)grp * 65536;
  float s = 0.f, ss = 0.f;
  for (int i = threadIdx.x; i < 16384; i += 256) {
    float4 v = *(const float4*)(p + (size_t)i * 4);
    s  += v.x + v.y + v.z + v.w;
    ss += v.x*v.x + v.y*v.y + v.z*v.z + v.w*v.w;
  }
  for (int off = 32; off; off >>= 1) { s += __shfl_down(s, off); ss += __shfl_down(ss, off); }
  __shared__ float red[8];
  int w = threadIdx.x >> 6;
  if ((threadIdx.x & 63) == 0) { red[w] = s; red[w + 4] = ss; }
  __syncthreads();
  if (threadIdx.x == 0) {
    s  = red[0] + red[1] + red[2] + red[3];
    ss = red[4] + red[5] + red[6] + red[7];
    float mean = s * (1.f / 65536.f);
    float var  = ss * (1.f / 65536.f) - mean * mean;
    stats[grp * 2]     = mean;
    stats[grp * 2 + 1] = rsqrtf(var + 1e-6f);
  }
}

// ---------------- GN apply + transpose: x[b][c][p] -> hn_t[b][p][c] bf16 ----------------
__global__ __launch_bounds__(256) void gn_apply(const float* __restrict__ x,
                                                const float* __restrict__ stats,
                                                const float* __restrict__ gamma,
                                                const float* __restrict__ beta,
                                                unsigned short* __restrict__ hn_t){
  __shared__ float tile[32][33];
  int b  = blockIdx.z;
  int c0 = blockIdx.y * 32;
  int p0 = blockIdx.x * 32;
  int tx = threadIdx.x & 31, ty = threadIdx.x >> 5;
  const float* xb = x + (size_t)b * 512 * 4096;
#pragma unroll
  for (int i = 0; i < 32; i += 8)
    tile[ty + i][tx] = xb[(size_t)(c0 + ty + i) * 4096 + p0 + tx];
  __syncthreads();
  unsigned short* hb = hn_t + (size_t)b * 4096 * 512;
  int c = c0 + tx;
  float mean = stats[(b * 32 + (c >> 4)) * 2];
  float rstd = stats[(b * 32 + (c >> 4)) * 2 + 1];
  float ga = gamma[c], be = beta[c];
#pragma unroll
  for (int i = 0; i < 32; i += 8) {
    float v = tile[tx][ty + i];
    hb[(size_t)(p0 + ty + i) * 512 + c] = f2bf((v - mean) * rstd * ga + be);
  }
}

// ---------------- GEMM: C[M,N] = A[M,K] * B[N,K]^T (bf16 in, fp32 accum) ----------------
// MODE 1: +bias[col] -> bf16 C            (Q,K proj;  auxA=bias)
// MODE 2: +bias[row] -> bf16 C            (V proj;    auxA=bias)
// MODE 3: P=mask[col]*exp(acc*scale) -> bf16 C, row-partial sums -> auxW[b][64][M] (scores; auxA=mask)
// MODE 4: acc*rinv[row] -> bf16 C         (PV;        auxA=rinv)
// MODE 5: acc + resid + bias[col] -> fp32 OUTF[b][col][p], transposed (O-proj; auxA=resid, auxB=bias)
template<int MODE>
__global__ __launch_bounds__(256)
void gemm_bt(const unsigned short* __restrict__ A,
             const unsigned short* __restrict__ B,
             unsigned short* __restrict__ C,
             float* __restrict__ OUTF,
             const float* __restrict__ auxA,
             const float* __restrict__ auxB,
             float* __restrict__ auxW,
             int M, int N, int K, float scale,
             size_t sA, size_t sB, size_t sC)
{
  __shared__ __align__(16) unsigned short As[128 * 32];
  __shared__ __align__(16) unsigned short Bs[128 * 32];
  const unsigned short* Ab = A + (size_t)blockIdx.z * sA;
  const unsigned short* Bb = B + (size_t)blockIdx.z * sB;
  const int brow = blockIdx.x * 128;
  const int bcol = blockIdx.y * 128;
  const int t = threadIdx.x;
  const int lane = t & 63;
  const int wid = t >> 6;
  const int wr = wid >> 1, wc = wid & 1;

  const f32x4 zero = {0.f, 0.f, 0.f, 0.f};
  f32x4 acc[4][4];
#pragma unroll
  for (int m = 0; m < 4; m++)
#pragma unroll
    for (int n = 0; n < 4; n++) acc[m][n] = zero;

  // global_load_lds staging, linear LDS dest; swizzle moved to the GLOBAL source:
  // LDS pos (row r, slot s') holds global chunk (r, s' ^ ((r>>1)&3))
  const int r0 = t >> 2;
  const int r1 = 64 + r0;
  const int sg0 = (((t & 3) ^ ((r0 >> 1) & 3))) * 8;
  const int sg1 = (((t & 3) ^ ((r1 >> 1) & 3))) * 8;
  const unsigned short* gA0 = Ab + (size_t)(brow + r0) * K + sg0;
  const unsigned short* gA1 = Ab + (size_t)(brow + r1) * K + sg1;
  const unsigned short* gB0 = Bb + (size_t)(bcol + r0) * K + sg0;
  const unsigned short* gB1 = Bb + (size_t)(bcol + r1) * K + sg1;
  unsigned short* lA0 = &As[t * 8];
  unsigned short* lA1 = &As[2048 + t * 8];
  unsigned short* lB0 = &Bs[t * 8];
  unsigned short* lB1 = &Bs[2048 + t * 8];

  const int arow = wr * 64 + (lane & 15);
  const int brw  = wc * 64 + (lane & 15);
  const int ka  = (((lane >> 4) ^ ((arow >> 1) & 3)) * 8);  // invariant under +16 rows
  const int kb2 = (((lane >> 4) ^ ((brw  >> 1) & 3)) * 8);

  const int nk = K >> 5;
  for (int kt = 0; kt < nk; ++kt) {
    __syncthreads();
    const int ko = kt * 32;
    gl_lds16(gA0 + ko, lA0);
    gl_lds16(gA1 + ko, lA1);
    gl_lds16(gB0 + ko, lB0);
    gl_lds16(gB1 + ko, lB1);
    __syncthreads();
    bf16x8 af[4], bfr[4];
#pragma unroll
    for (int m = 0; m < 4; m++)
      af[m] = __builtin_bit_cast(bf16x8, *(const u16x8*)&As[(arow + m * 16) * 32 + ka]);
#pragma unroll
    for (int n = 0; n < 4; n++)
      bfr[n] = __builtin_bit_cast(bf16x8, *(const u16x8*)&Bs[(brw + n * 16) * 32 + kb2]);
#pragma unroll
    for (int m = 0; m < 4; m++)
#pragma unroll
      for (int n = 0; n < 4; n++)
        acc[m][n] = __builtin_amdgcn_mfma_f32_16x16x32_bf16(af[m], bfr[n], acc[m][n], 0, 0, 0);
  }

  // epilogue: C/D layout col=lane&15, row=(lane>>4)*4+j
  const int cl = lane & 15;
  const int rg = (lane >> 4) * 4;

  if (MODE == 1 || MODE == 2) {
    unsigned short* Cb = C + (size_t)blockIdx.z * sC;
#pragma unroll
    for (int m = 0; m < 4; m++) {
#pragma unroll
      for (int n = 0; n < 4; n++) {
        const int col = bcol + wc * 64 + n * 16 + cl;
        const float bcv = (MODE == 1) ? auxA[col] : 0.f;
#pragma unroll
        for (int j = 0; j < 4; j++) {
          const int row = brow + wr * 64 + m * 16 + rg + j;
          float v = acc[m][n][j] + bcv + ((MODE == 2) ? auxA[row] : 0.f);
          Cb[(size_t)row * N + col] = f2bf(v);
        }
      }
    }
  } else if (MODE == 3) {
    unsigned short* Cb = C + (size_t)blockIdx.z * sC;
    const float* maskb = auxA + (size_t)blockIdx.z * 4096;
    float* partb = auxW + ((size_t)blockIdx.z * 64 + (size_t)(blockIdx.y * 2 + wc)) * M;
    float rowsum[16];
#pragma unroll
    for (int i = 0; i < 16; i++) rowsum[i] = 0.f;
#pragma unroll
    for (int m = 0; m < 4; m++) {
#pragma unroll
      for (int n = 0; n < 4; n++) {
        const int col = bcol + wc * 64 + n * 16 + cl;
        const float mk = maskb[col];
#pragma unroll
        for (int j = 0; j < 4; j++) {
          const int row = brow + wr * 64 + m * 16 + rg + j;
          float v = mk * __expf(acc[m][n][j] * scale);
          unsigned short hv = f2bf(v);
          rowsum[m * 4 + j] += bf2f(hv);
          Cb[(size_t)row * N + col] = hv;
        }
      }
    }
#pragma unroll
    for (int off = 1; off < 16; off <<= 1)
#pragma unroll
      for (int i = 0; i < 16; i++) rowsum[i] += __shfl_xor(rowsum[i], off);
    if (cl == 0) {
#pragma unroll
      for (int m = 0; m < 4; m++) {
        float4 v = make_float4(rowsum[m*4], rowsum[m*4+1], rowsum[m*4+2], rowsum[m*4+3]);
        *(float4*)&partb[brow + wr * 64 + m * 16 + rg] = v;
      }
    }
  } else if (MODE == 4) {
    unsigned short* Cb = C + (size_t)blockIdx.z * sC;
    const float* rb = auxA + (size_t)blockIdx.z * 4096;
#pragma unroll
    for (int m = 0; m < 4; m++) {
      const float4 ri = *(const float4*)&rb[brow + wr * 64 + m * 16 + rg];
      const float riv[4] = {ri.x, ri.y, ri.z, ri.w};
#pragma unroll
      for (int n = 0; n < 4; n++) {
        const int col = bcol + wc * 64 + n * 16 + cl;
#pragma unroll
        for (int j = 0; j < 4; j++) {
          const int row = brow + wr * 64 + m * 16 + rg + j;
          Cb[(size_t)row * N + col] = f2bf(acc[m][n][j] * riv[j]);
        }
      }
    }
  } else { // MODE 5
#pragma unroll
    for (int m = 0; m < 4; m++) {
      const int row = brow + wr * 64 + m * 16 + rg;
      const int bb = row >> 12;
      const int p  = row & 4095;
#pragma unroll
      for (int n = 0; n < 4; n++) {
        const int col = bcol + wc * 64 + n * 16 + cl;
        const size_t idx = ((size_t)bb * 512 + col) * 4096 + p;
        const float4 xv = *(const float4*)&auxA[idx];
        const float bv = auxB[col];
        float4 ov;
        ov.x = acc[m][n][0] + xv.x + bv;
        ov.y = acc[m][n][1] + xv.y + bv;
        ov.z = acc[m][n][2] + xv.z + bv;
        ov.w = acc[m][n][3] + xv.w + bv;
        *(float4*)&OUTF[idx] = ov;
      }
    }
  }
}

// ---------------- rowsum reduce: rinv[b][q] = 1 / sum_i partial[b][i][q] ----------------
__global__ __launch_bounds__(256) void rowsum_inv(const float* __restrict__ partial,
                                                  float* __restrict__ rinv){
  const int idx = blockIdx.x * 256 + threadIdx.x;   // 16384
  const int b = idx >> 12, q = idx & 4095;
  const float* p = partial + ((size_t)b * 64) * 4096 + q;
  float s = 0.f;
#pragma unroll
  for (int i = 0; i < 64; i++) s += p[(size_t)i * 4096];
  rinv[idx] = 1.f / s;
}

extern "C" void kernel_launch(void* const* d_in, const int* in_sizes, int n_in,
                              void* d_out, int out_size, void* d_ws, size_t ws_size,
                              hipStream_t stream) {
  const float* x     = (const float*)d_in[0];
  const float* mask  = (const float*)d_in[1];
  const float* gamma = (const float*)d_in[2];
  const float* beta  = (const float*)d_in[3];
  const float* Wq    = (const float*)d_in[4];
  const float* bq    = (const float*)d_in[5];
  const float* Wk    = (const float*)d_in[6];
  const float* bk    = (const float*)d_in[7];
  const float* Wv    = (const float*)d_in[8];
  const float* bv    = (const float*)d_in[9];
  const float* Wo    = (const float*)d_in[10];
  const float* bo    = (const float*)d_in[11];
  float* out = (float*)d_out;

  size_t off = 0;
  auto nxt = [&](size_t bytes) -> void* {
    void* p = (char*)d_ws + off;
    off += (bytes + 255) & ~(size_t)255;
    return p;
  };
  float* stats          = (float*)nxt(256 * sizeof(float));
  float* partial        = (float*)nxt((size_t)4 * 64 * 4096 * 4);
  float* rinv           = (float*)nxt((size_t)16384 * 4);
  unsigned short* Wqb   = (unsigned short*)nxt((size_t)512 * 512 * 2);
  unsigned short* Wkb   = (unsigned short*)nxt((size_t)512 * 512 * 2);
  unsigned short* Wvb   = (unsigned short*)nxt((size_t)512 * 512 * 2);
  unsigned short* Wob   = (unsigned short*)nxt((size_t)512 * 512 * 2);
  unsigned short* hnt   = (unsigned short*)nxt((size_t)16384 * 512 * 2); // [b*4096+p][c]
  unsigned short* qt    = (unsigned short*)nxt((size_t)16384 * 512 * 2);
  unsigned short* ktb   = (unsigned short*)nxt((size_t)16384 * 512 * 2);
  unsigned short* vcm   = (unsigned short*)nxt((size_t)16384 * 512 * 2); // [b][c][p]
  unsigned short* ot    = (unsigned short*)nxt((size_t)16384 * 512 * 2); // [b*4096+p][c]
  unsigned short* P     = (unsigned short*)nxt((size_t)4 * 4096 * 4096 * 2);

  f32_to_bf16<<<128, 256, 0, stream>>>(Wq, Wqb, 262144);
  f32_to_bf16<<<128, 256, 0, stream>>>(Wk, Wkb, 262144);
  f32_to_bf16<<<128, 256, 0, stream>>>(Wv, Wvb, 262144);
  f32_to_bf16<<<128, 256, 0, stream>>>(Wo, Wob, 262144);

  gn_stats<<<128, 256, 0, stream>>>(x, stats);
  gn_apply<<<dim3(128, 16, 4), 256, 0, stream>>>(x, stats, gamma, beta, hnt);

  // Q, K: [16384,512] = hn_t x W^T (+ per-col bias)
  gemm_bt<1><<<dim3(128, 4, 1), 256, 0, stream>>>(hnt, Wqb, qt, nullptr, bq, nullptr, nullptr,
                                                  16384, 512, 512, 1.f, 0, 0, 0);
  gemm_bt<1><<<dim3(128, 4, 1), 256, 0, stream>>>(hnt, Wkb, ktb, nullptr, bk, nullptr, nullptr,
                                                  16384, 512, 512, 1.f, 0, 0, 0);
  // V channel-major: v_cm[b][c][p] (+ per-row bias)
  gemm_bt<2><<<dim3(4, 32, 4), 256, 0, stream>>>(Wvb, hnt, vcm, nullptr, bv, nullptr, nullptr,
                                                 512, 4096, 512, 1.f,
                                                 0, (size_t)4096 * 512, (size_t)512 * 4096);
  // scores -> P_un = mask*exp(s*scale) (bf16) + row partial sums
  gemm_bt<3><<<dim3(32, 32, 4), 256, 0, stream>>>(qt, ktb, P, nullptr, mask, nullptr, partial,
                                                  4096, 4096, 512, 0.044194173824159216f,
                                                  (size_t)4096 * 512, (size_t)4096 * 512,
                                                  (size_t)4096 * 4096);
  rowsum_inv<<<64, 256, 0, stream>>>(partial, rinv);
  // PV: ot[b][qi][c] = (P_un x v_cm^T) * rinv[qi]
  gemm_bt<4><<<dim3(32, 4, 4), 256, 0, stream>>>(P, vcm, ot, nullptr, rinv, nullptr, nullptr,
                                                 4096, 512, 4096, 1.f,
                                                 (size_t)4096 * 4096, (size_t)512 * 4096,
                                                 (size_t)4096 * 512);
  // O-projection + residual + bias, transposed write to d_out[b][c][p]
  gemm_bt<5><<<dim3(128, 4, 1), 256, 0, stream>>>(ot, Wob, nullptr, out, x, bo, nullptr,
                                                  16384, 512, 512, 1.f, 0, 0, 0);
}

// Round 3
// 357.207 us; speedup vs baseline: 1.0481x; 1.0418x over previous
//
#include <hip/hip_runtime.h>
#include <hip/hip_bf16.h>
#include <stdint.h>

typedef __attribute__((ext_vector_type(4))) float f32x4;
typedef __attribute__((ext_vector_type(8))) __bf16 bf16x8;
typedef __attribute__((ext_vector_type(8))) unsigned short u16x8;

__device__ __forceinline__ unsigned short f2bf(float f){
  uint32_t u = __builtin_bit_cast(uint32_t, f);
  u += 0x7FFFu + ((u >> 16) & 1u);
  return (unsigned short)(u >> 16);
}
__device__ __forceinline__ float bf2f(unsigned short h){
  return __builtin_bit_cast(float, ((uint32_t)h) << 16);
}
__device__ __forceinline__ float fast_exp2(float x){
#if __has_builtin(__builtin_amdgcn_exp2f)
  return __builtin_amdgcn_exp2f(x);
#else
  return exp2f(x);
#endif
}
__device__ __forceinline__ void gl_lds16(const unsigned short* g, unsigned short* l){
  __builtin_amdgcn_global_load_lds(
      (const __attribute__((address_space(1))) uint32_t*)g,
      (__attribute__((address_space(3))) uint32_t*)l, 16, 0, 0);
}

// ---------------- fp32 -> bf16 convert (weights) ----------------
__global__ __launch_bounds__(256) void f32_to_bf16(const float* __restrict__ in,
                                                   unsigned short* __restrict__ out, int n){
  int i = (blockIdx.x * 256 + threadIdx.x) * 8;
  if (i + 8 <= n) {
    float4 a = *(const float4*)&in[i];
    float4 b = *(const float4*)&in[i + 4];
    u16x8 o;
    o[0]=f2bf(a.x); o[1]=f2bf(a.y); o[2]=f2bf(a.z); o[3]=f2bf(a.w);
    o[4]=f2bf(b.x); o[5]=f2bf(b.y); o[6]=f2bf(b.z); o[7]=f2bf(b.w);
    *(u16x8*)&out[i] = o;
  }
}

// ---------------- GroupNorm stats ----------------
__global__ __launch_bounds__(256) void gn_stats(const float* __restrict__ x,
                                                float* __restrict__ stats){
  int grp = blockIdx.x; // b*32+g, 128 total
  const float* p = x + (size_t)grp * 65536;
  float s = 0.f, ss = 0.f;
  for (int i = threadIdx.x; i < 16384; i += 256) {
    float4 v = *(const float4*)(p + (size_t)i * 4);
    s  += v.x + v.y + v.z + v.w;
    ss += v.x*v.x + v.y*v.y + v.z*v.z + v.w*v.w;
  }
  for (int off = 32; off; off >>= 1) { s += __shfl_down(s, off); ss += __shfl_down(ss, off); }
  __shared__ float red[8];
  int w = threadIdx.x >> 6;
  if ((threadIdx.x & 63) == 0) { red[w] = s; red[w + 4] = ss; }
  __syncthreads();
  if (threadIdx.x == 0) {
    s  = red[0] + red[1] + red[2] + red[3];
    ss = red[4] + red[5] + red[6] + red[7];
    float mean = s * (1.f / 65536.f);
    float var  = ss * (1.f / 65536.f) - mean * mean;
    stats[grp * 2]     = mean;
    stats[grp * 2 + 1] = rsqrtf(var + 1e-6f);
  }
}

// ---------------- GN apply + transpose ----------------
__global__ __launch_bounds__(256) void gn_apply(const float* __restrict__ x,
                                                const float* __restrict__ stats,
                                                const float* __restrict__ gamma,
                                                const float* __restrict__ beta,
                                                unsigned short* __restrict__ hn_t){
  __shared__ float tile[32][33];
  int b  = blockIdx.z;
  int c0 = blockIdx.y * 32;
  int p0 = blockIdx.x * 32;
  int tx = threadIdx.x & 31, ty = threadIdx.x >> 5;
  const float* xb = x + (size_t)b * 512 * 4096;
#pragma unroll
  for (int i = 0; i < 32; i += 8)
    tile[ty + i][tx] = xb[(size_t)(c0 + ty + i) * 4096 + p0 + tx];
  __syncthreads();
  unsigned short* hb = hn_t + (size_t)b * 4096 * 512;
  int c = c0 + tx;
  float mean = stats[(b * 32 + (c >> 4)) * 2];
  float rstd = stats[(b * 32 + (c >> 4)) * 2 + 1];
  float ga = gamma[c], be = beta[c];
#pragma unroll
  for (int i = 0; i < 32; i += 8) {
    float v = tile[tx][ty + i];
    hb[(size_t)(p0 + ty + i) * 512 + c] = f2bf((v - mean) * rstd * ga + be);
  }
}

// ---------------- unified GEMM body: C[M,N] = A[M,K]*B[N,K]^T ----------------
// MODE 1: +bias[col]->bf16 | 2: +bias[row]->bf16 | 3: mask*exp2(acc*sc)->bf16 + partials
// MODE 4: acc*rinv[row]->bf16 | 5: acc+resid+bias[col]->fp32 transposed
template<int MODE>
__device__ __forceinline__ void gemm_body(
    const unsigned short* __restrict__ A, const unsigned short* __restrict__ B,
    unsigned short* __restrict__ C, float* __restrict__ OUTF,
    const float* __restrict__ auxA, const float* __restrict__ auxB,
    float* __restrict__ auxW,
    int M, int N, int K, float scale,
    size_t sA, size_t sB, size_t sC, int gx, int gy)
{
  __shared__ __align__(16) unsigned short As[8192]; // 2 bufs x 128x32
  __shared__ __align__(16) unsigned short Bs[8192];

  // XCD-aware bijective swizzle (nwg % 8 == 0 for all launches)
  const int lin = blockIdx.x;
  const int nwg = gridDim.x;
  const int wg = ((lin & 7) * (nwg >> 3)) + (lin >> 3);
  const int bx = wg % gx;
  const int t2 = wg / gx;
  const int by = t2 % gy;
  const int bz = t2 / gy;

  const unsigned short* Ab = A + (size_t)bz * sA;
  const unsigned short* Bb = B + (size_t)bz * sB;
  const int brow = bx * 128;
  const int bcol = by * 128;
  const int t = threadIdx.x;
  const int lane = t & 63;
  const int wid = t >> 6;
  const int wr = wid >> 1, wc = wid & 1;

  const f32x4 zero = {0.f, 0.f, 0.f, 0.f};
  f32x4 acc[4][4];
#pragma unroll
  for (int m = 0; m < 4; m++)
#pragma unroll
    for (int n = 0; n < 4; n++) acc[m][n] = zero;

  // staging: linear LDS dest, swizzle on the GLOBAL source:
  // LDS (row r, slot s') holds global chunk (r, s' ^ ((r>>1)&3))
  const int r0 = t >> 2;
  const int r1 = 64 + r0;
  const int sg0 = (((t & 3) ^ ((r0 >> 1) & 3))) * 8;
  const int sg1 = (((t & 3) ^ ((r1 >> 1) & 3))) * 8;
  const unsigned short* gA0 = Ab + (size_t)(brow + r0) * K + sg0;
  const unsigned short* gA1 = Ab + (size_t)(brow + r1) * K + sg1;
  const unsigned short* gB0 = Bb + (size_t)(bcol + r0) * K + sg0;
  const unsigned short* gB1 = Bb + (size_t)(bcol + r1) * K + sg1;

  const int arow = wr * 64 + (lane & 15);
  const int brw  = wc * 64 + (lane & 15);
  const int ka  = (((lane >> 4) ^ ((arow >> 1) & 3)) * 8);  // +16-row invariant
  const int kb2 = (((lane >> 4) ^ ((brw  >> 1) & 3)) * 8);

  auto STAGE = [&](int kt, int buf) {
    const int ko = kt * 32;
    unsigned short* a = As + buf * 4096;
    unsigned short* b = Bs + buf * 4096;
    gl_lds16(gA0 + ko, a + t * 8);
    gl_lds16(gA1 + ko, a + 2048 + t * 8);
    gl_lds16(gB0 + ko, b + t * 8);
    gl_lds16(gB1 + ko, b + 2048 + t * 8);
  };
  auto COMPUTE = [&](int buf) {
    const unsigned short* a = As + buf * 4096;
    const unsigned short* b = Bs + buf * 4096;
    bf16x8 af[4], bfr[4];
#pragma unroll
    for (int m = 0; m < 4; m++)
      af[m] = __builtin_bit_cast(bf16x8, *(const u16x8*)&a[(arow + m * 16) * 32 + ka]);
#pragma unroll
    for (int n = 0; n < 4; n++)
      bfr[n] = __builtin_bit_cast(bf16x8, *(const u16x8*)&b[(brw + n * 16) * 32 + kb2]);
#pragma unroll
    for (int m = 0; m < 4; m++)
#pragma unroll
      for (int n = 0; n < 4; n++)
        acc[m][n] = __builtin_amdgcn_mfma_f32_16x16x32_bf16(af[m], bfr[n], acc[m][n], 0, 0, 0);
  };

  const int nk = K >> 5;
  STAGE(0, 0);
  int cur = 0;
  for (int kt = 0; kt < nk - 1; ++kt) {
    STAGE(kt + 1, cur ^ 1);
    __builtin_amdgcn_sched_barrier(0);
    asm volatile("s_waitcnt vmcnt(4)" ::: "memory");
    __builtin_amdgcn_sched_barrier(0);
    __builtin_amdgcn_s_barrier();
    __builtin_amdgcn_sched_barrier(0);
    COMPUTE(cur);
    __builtin_amdgcn_sched_barrier(0);
    __builtin_amdgcn_s_barrier();
    __builtin_amdgcn_sched_barrier(0);
    cur ^= 1;
  }
  __builtin_amdgcn_sched_barrier(0);
  asm volatile("s_waitcnt vmcnt(0)" ::: "memory");
  __builtin_amdgcn_sched_barrier(0);
  __builtin_amdgcn_s_barrier();
  __builtin_amdgcn_sched_barrier(0);
  COMPUTE(cur);

  // epilogue: C/D layout col=lane&15, row=(lane>>4)*4+j
  const int cl = lane & 15;
  const int rg = (lane >> 4) * 4;

  if (MODE == 1 || MODE == 2) {
    unsigned short* Cb = C + (size_t)bz * sC;
#pragma unroll
    for (int m = 0; m < 4; m++) {
#pragma unroll
      for (int n = 0; n < 4; n++) {
        const int col = bcol + wc * 64 + n * 16 + cl;
        const float bcv = (MODE == 1) ? auxA[col] : 0.f;
#pragma unroll
        for (int j = 0; j < 4; j++) {
          const int row = brow + wr * 64 + m * 16 + rg + j;
          float v = acc[m][n][j] + bcv + ((MODE == 2) ? auxA[row] : 0.f);
          Cb[(size_t)row * N + col] = f2bf(v);
        }
      }
    }
  } else if (MODE == 3) {
    unsigned short* Cb = C + (size_t)bz * sC;
    const float* maskb = auxA + (size_t)bz * 4096;
    float* partb = auxW + ((size_t)bz * 64 + (size_t)(by * 2 + wc)) * M;
    const float sc2 = scale * 1.4426950408889634f;
    float rowsum[16];
#pragma unroll
    for (int i = 0; i < 16; i++) rowsum[i] = 0.f;
#pragma unroll
    for (int m = 0; m < 4; m++) {
#pragma unroll
      for (int n = 0; n < 4; n++) {
        const int col = bcol + wc * 64 + n * 16 + cl;
        const float mk = maskb[col];
#pragma unroll
        for (int j = 0; j < 4; j++) {
          const int row = brow + wr * 64 + m * 16 + rg + j;
          float v = mk * fast_exp2(acc[m][n][j] * sc2);
          rowsum[m * 4 + j] += v;
          Cb[(size_t)row * N + col] = f2bf(v);
        }
      }
    }
#pragma unroll
    for (int off = 1; off < 16; off <<= 1)
#pragma unroll
      for (int i = 0; i < 16; i++) rowsum[i] += __shfl_xor(rowsum[i], off);
    if (cl == 0) {
#pragma unroll
      for (int m = 0; m < 4; m++) {
        float4 v = make_float4(rowsum[m*4], rowsum[m*4+1], rowsum[m*4+2], rowsum[m*4+3]);
        *(float4*)&partb[brow + wr * 64 + m * 16 + rg] = v;
      }
    }
  } else if (MODE == 4) {
    unsigned short* Cb = C + (size_t)bz * sC;
    const float* rb = auxA + (size_t)bz * 4096;
#pragma unroll
    for (int m = 0; m < 4; m++) {
      const float4 ri = *(const float4*)&rb[brow + wr * 64 + m * 16 + rg];
      const float riv[4] = {ri.x, ri.y, ri.z, ri.w};
#pragma unroll
      for (int n = 0; n < 4; n++) {
        const int col = bcol + wc * 64 + n * 16 + cl;
#pragma unroll
        for (int j = 0; j < 4; j++) {
          const int row = brow + wr * 64 + m * 16 + rg + j;
          Cb[(size_t)row * N + col] = f2bf(acc[m][n][j] * riv[j]);
        }
      }
    }
  } else { // MODE 5
#pragma unroll
    for (int m = 0; m < 4; m++) {
      const int row = brow + wr * 64 + m * 16 + rg;
      const int bb = row >> 12;
      const int p  = row & 4095;
#pragma unroll
      for (int n = 0; n < 4; n++) {
        const int col = bcol + wc * 64 + n * 16 + cl;
        const size_t idx = ((size_t)bb * 512 + col) * 4096 + p;
        const float4 xv = *(const float4*)&auxA[idx];
        const float bv = auxB[col];
        float4 ov;
        ov.x = acc[m][n][0] + xv.x + bv;
        ov.y = acc[m][n][1] + xv.y + bv;
        ov.z = acc[m][n][2] + xv.z + bv;
        ov.w = acc[m][n][3] + xv.w + bv;
        *(float4*)&OUTF[idx] = ov;
      }
    }
  }
}

#define GEMM_ARGS const unsigned short* A, const unsigned short* B, unsigned short* C, \
                  float* OUTF, const float* auxA, const float* auxB, float* auxW, \
                  int M, int N, int K, float scale, size_t sA, size_t sB, size_t sC, int gx, int gy
#define GEMM_PASS A, B, C, OUTF, auxA, auxB, auxW, M, N, K, scale, sA, sB, sC, gx, gy

__global__ __launch_bounds__(256) void k_qkproj(GEMM_ARGS){ gemm_body<1>(GEMM_PASS); }
__global__ __launch_bounds__(256) void k_vproj (GEMM_ARGS){ gemm_body<2>(GEMM_PASS); }
__global__ __launch_bounds__(256) void k_scores(GEMM_ARGS){ gemm_body<3>(GEMM_PASS); }
__global__ __launch_bounds__(256) void k_pv    (GEMM_ARGS){ gemm_body<4>(GEMM_PASS); }
__global__ __launch_bounds__(256) void k_oproj (GEMM_ARGS){ gemm_body<5>(GEMM_PASS); }

// ---------------- rowsum reduce ----------------
__global__ __launch_bounds__(256) void rowsum_inv(const float* __restrict__ partial,
                                                  float* __restrict__ rinv){
  const int idx = blockIdx.x * 256 + threadIdx.x;   // 16384
  const int b = idx >> 12, q = idx & 4095;
  const float* p = partial + ((size_t)b * 64) * 4096 + q;
  float s = 0.f;
#pragma unroll
  for (int i = 0; i < 64; i++) s += p[(size_t)i * 4096];
  rinv[idx] = 1.f / s;
}

extern "C" void kernel_launch(void* const* d_in, const int* in_sizes, int n_in,
                              void* d_out, int out_size, void* d_ws, size_t ws_size,
                              hipStream_t stream) {
  const float* x     = (const float*)d_in[0];
  const float* mask  = (const float*)d_in[1];
  const float* gamma = (const float*)d_in[2];
  const float* beta  = (const float*)d_in[3];
  const float* Wq    = (const float*)d_in[4];
  const float* bq    = (const float*)d_in[5];
  const float* Wk    = (const float*)d_in[6];
  const float* bk    = (const float*)d_in[7];
  const float* Wv    = (const float*)d_in[8];
  const float* bv    = (const float*)d_in[9];
  const float* Wo    = (const float*)d_in[10];
  const float* bo    = (const float*)d_in[11];
  float* out = (float*)d_out;

  size_t off = 0;
  auto nxt = [&](size_t bytes) -> void* {
    void* p = (char*)d_ws + off;
    off += (bytes + 255) & ~(size_t)255;
    return p;
  };
  float* stats          = (float*)nxt(256 * sizeof(float));
  float* partial        = (float*)nxt((size_t)4 * 64 * 4096 * 4);
  float* rinv           = (float*)nxt((size_t)16384 * 4);
  unsigned short* Wqb   = (unsigned short*)nxt((size_t)512 * 512 * 2);
  unsigned short* Wkb   = (unsigned short*)nxt((size_t)512 * 512 * 2);
  unsigned short* Wvb   = (unsigned short*)nxt((size_t)512 * 512 * 2);
  unsigned short* Wob   = (unsigned short*)nxt((size_t)512 * 512 * 2);
  unsigned short* hnt   = (unsigned short*)nxt((size_t)16384 * 512 * 2);
  unsigned short* qt    = (unsigned short*)nxt((size_t)16384 * 512 * 2);
  unsigned short* ktb   = (unsigned short*)nxt((size_t)16384 * 512 * 2);
  unsigned short* vcm   = (unsigned short*)nxt((size_t)16384 * 512 * 2);
  unsigned short* ot    = (unsigned short*)nxt((size_t)16384 * 512 * 2);
  unsigned short* P     = (unsigned short*)nxt((size_t)4 * 4096 * 4096 * 2);

  f32_to_bf16<<<128, 256, 0, stream>>>(Wq, Wqb, 262144);
  f32_to_bf16<<<128, 256, 0, stream>>>(Wk, Wkb, 262144);
  f32_to_bf16<<<128, 256, 0, stream>>>(Wv, Wvb, 262144);
  f32_to_bf16<<<128, 256, 0, stream>>>(Wo, Wob, 262144);

  gn_stats<<<128, 256, 0, stream>>>(x, stats);
  gn_apply<<<dim3(128, 16, 4), 256, 0, stream>>>(x, stats, gamma, beta, hnt);

  // Q, K: [16384,512] = hn_t x W^T (+ per-col bias); gx=128, gy=4, gz=1
  k_qkproj<<<512, 256, 0, stream>>>(hnt, Wqb, qt, nullptr, bq, nullptr, nullptr,
                                    16384, 512, 512, 1.f, 0, 0, 0, 128, 4);
  k_qkproj<<<512, 256, 0, stream>>>(hnt, Wkb, ktb, nullptr, bk, nullptr, nullptr,
                                    16384, 512, 512, 1.f, 0, 0, 0, 128, 4);
  // V channel-major: v_cm[b][c][p] (+ per-row bias); gx=4, gy=32, gz=4
  k_vproj<<<512, 256, 0, stream>>>(Wvb, hnt, vcm, nullptr, bv, nullptr, nullptr,
                                   512, 4096, 512, 1.f,
                                   0, (size_t)4096 * 512, (size_t)512 * 4096, 4, 32);
  // scores -> P_un = mask*exp(s*scale) (bf16) + row partial sums; gx=32, gy=32, gz=4
  k_scores<<<4096, 256, 0, stream>>>(qt, ktb, P, nullptr, mask, nullptr, partial,
                                     4096, 4096, 512, 0.044194173824159216f,
                                     (size_t)4096 * 512, (size_t)4096 * 512,
                                     (size_t)4096 * 4096, 32, 32);
  rowsum_inv<<<64, 256, 0, stream>>>(partial, rinv);
  // PV: ot[b][qi][c] = (P_un x v_cm^T) * rinv[qi]; gx=32, gy=4, gz=4
  k_pv<<<512, 256, 0, stream>>>(P, vcm, ot, nullptr, rinv, nullptr, nullptr,
                                4096, 512, 4096, 1.f,
                                (size_t)4096 * 4096, (size_t)512 * 4096,
                                (size_t)4096 * 512, 32, 4);
  // O-projection + residual + bias -> fp32 out; gx=128, gy=4, gz=1
  k_oproj<<<512, 256, 0, stream>>>(ot, Wob, nullptr, out, x, bo, nullptr,
                                   16384, 512, 512, 1.f, 0, 0, 0, 128, 4);
}